// Round 1
// baseline (989.030 us; speedup 1.0000x reference)
//
#include <hip/hip_runtime.h>
#include <hip/hip_bf16.h>

// Problem constants
#define B 32
#define T 2048
#define E 512
#define D 1024
#define H 128

#define TB 32   // t-rows per erg block
#define KC 64   // k-chunk held in registers

// ---------------------------------------------------------------------------
// Kernel 1: dec[b][h] = b_enc[h] + sum_k decoder_state[b][k] * W_dec[k][h]
// Also zeroes the context output region (stream-ordered before ctx_kernel).
// ---------------------------------------------------------------------------
__global__ __launch_bounds__(512) void dec_kernel(
    const float* __restrict__ ds, const float* __restrict__ Wd,
    const float* __restrict__ be, float* __restrict__ dec_ws,
    float* __restrict__ ctx_out) {
  const int b = blockIdx.x;
  const int tid = threadIdx.x;
  const int h = tid & 127;
  const int kg = tid >> 7;  // 0..3, each covers 256 k
  __shared__ float sds[D];
  __shared__ float sred[4][H];
  for (int i = tid; i < D; i += 512) sds[i] = ds[b * D + i];
  ctx_out[b * E + tid] = 0.0f;  // zero 512 context floats for this b
  __syncthreads();
  float acc = 0.0f;
  const int k0 = kg * 256;
#pragma unroll 8
  for (int k = k0; k < k0 + 256; ++k) acc = fmaf(sds[k], Wd[k * H + h], acc);
  sred[kg][h] = acc;
  __syncthreads();
  if (kg == 0)
    dec_ws[b * H + h] = be[h] + sred[0][h] + sred[1][h] + sred[2][h] + sred[3][h];
}

// ---------------------------------------------------------------------------
// Kernel 2: erg[b][t] = w_b + sum_h w_w[h]*tanh(dec[b][h] + enc[b][t][:]@W_enc[:,h])
// Block = 128 threads (one per h). 32 t-rows per block, serial.
// enc reads are block-uniform -> scalar loads; W_enc columns in VGPRs.
// ---------------------------------------------------------------------------
__global__ __launch_bounds__(128) void erg_kernel(
    const float* __restrict__ enc, const float* __restrict__ We,
    const float* __restrict__ dec_ws, const float* __restrict__ ww,
    const float* __restrict__ wb, float* __restrict__ erg_ws) {
  const int b = blockIdx.y;
  const int t0 = blockIdx.x * TB;
  const int h = threadIdx.x;  // 0..127

  float acc[TB];
  const float d = dec_ws[b * H + h];
#pragma unroll
  for (int i = 0; i < TB; ++i) acc[i] = d;

  const float* encb = enc + ((size_t)b * T + t0) * E;

  for (int kc = 0; kc < E / KC; ++kc) {
    float wr[KC];
#pragma unroll
    for (int k = 0; k < KC; ++k) wr[k] = We[(kc * KC + k) * H + h];
#pragma unroll
    for (int i = 0; i < TB; ++i) {
      const float4* er = (const float4*)(encb + (size_t)i * E + kc * KC);
#pragma unroll
      for (int k4 = 0; k4 < KC / 4; ++k4) {
        const float4 e = er[k4];  // block-uniform address -> s_load_dwordx4
        acc[i] = fmaf(e.x, wr[k4 * 4 + 0], acc[i]);
        acc[i] = fmaf(e.y, wr[k4 * 4 + 1], acc[i]);
        acc[i] = fmaf(e.z, wr[k4 * 4 + 2], acc[i]);
        acc[i] = fmaf(e.w, wr[k4 * 4 + 3], acc[i]);
      }
    }
  }

  // erg[t] = w_b + sum_h ww[h] * tanh(acc)
  const float wwv = ww[h];
  __shared__ float sred[2][TB];
  const int lane = h & 63, wid = h >> 6;
#pragma unroll
  for (int i = 0; i < TB; ++i) {
    const float x = acc[i];
    // tanh(x) = 1 - 2/(exp(2x)+1); exact limits at +-inf
    const float th = 1.0f - 2.0f / (__expf(2.0f * x) + 1.0f);
    float g = wwv * th;
#pragma unroll
    for (int off = 32; off > 0; off >>= 1) g += __shfl_xor(g, off, 64);
    if (lane == 0) sred[wid][i] = g;
  }
  __syncthreads();
  if (h < TB) erg_ws[b * T + t0 + h] = sred[0][h] + sred[1][h] + wb[0];
}

// ---------------------------------------------------------------------------
// Kernel 3: masked softmax over t. mask = (t >= src_lens[b]) -> weight 0.
// Writes attention_weights to d_out + B*E.
// ---------------------------------------------------------------------------
__global__ __launch_bounds__(256) void softmax_kernel(
    const float* __restrict__ erg_ws, const int* __restrict__ src_lens,
    float* __restrict__ wout) {
  const int b = blockIdx.x;
  const int n = src_lens[b];
  const int tid = threadIdx.x;
  const int lane = tid & 63, wid = tid >> 6;
  __shared__ float sm[4];

  float v[T / 256];
  float m = -1e30f;
#pragma unroll
  for (int r = 0; r < T / 256; ++r) {
    const int t = tid + r * 256;
    const float x = erg_ws[b * T + t];
    v[r] = (t < n) ? x : -1e30f;
    m = fmaxf(m, v[r]);
  }
#pragma unroll
  for (int off = 32; off > 0; off >>= 1) m = fmaxf(m, __shfl_xor(m, off, 64));
  if (lane == 0) sm[wid] = m;
  __syncthreads();
  m = fmaxf(fmaxf(sm[0], sm[1]), fmaxf(sm[2], sm[3]));
  __syncthreads();

  float s = 0.0f;
#pragma unroll
  for (int r = 0; r < T / 256; ++r) {
    const float e = (v[r] > -1e29f) ? __expf(v[r] - m) : 0.0f;
    v[r] = e;
    s += e;
  }
#pragma unroll
  for (int off = 32; off > 0; off >>= 1) s += __shfl_xor(s, off, 64);
  if (lane == 0) sm[wid] = s;
  __syncthreads();
  s = sm[0] + sm[1] + sm[2] + sm[3];
  const float inv = 1.0f / s;
#pragma unroll
  for (int r = 0; r < T / 256; ++r) wout[b * T + tid + r * 256] = v[r] * inv;
}

// ---------------------------------------------------------------------------
// Kernel 4: context[b][e] = sum_t enc[b][t][e] * weights[b][t]
// Each block: one b, 64-t chunk, 128 threads x float4 over E=512.
// ---------------------------------------------------------------------------
__global__ __launch_bounds__(128) void ctx_kernel(
    const float* __restrict__ enc, const float* __restrict__ w,
    float* __restrict__ ctx) {
  const int b = blockIdx.y;
  const int t0 = blockIdx.x * 64;
  const int tid = threadIdx.x;
  __shared__ float sw[64];
  if (tid < 64) sw[tid] = w[b * T + t0 + tid];
  __syncthreads();
  float4 acc = {0.0f, 0.0f, 0.0f, 0.0f};
  const float4* ep = (const float4*)(enc + ((size_t)b * T + t0) * E) + tid;
#pragma unroll 8
  for (int t = 0; t < 64; ++t) {
    const float4 e = ep[(size_t)t * (E / 4)];
    const float wv = sw[t];
    acc.x = fmaf(e.x, wv, acc.x);
    acc.y = fmaf(e.y, wv, acc.y);
    acc.z = fmaf(e.z, wv, acc.z);
    acc.w = fmaf(e.w, wv, acc.w);
  }
  float* c = ctx + b * E + tid * 4;
  atomicAdd(c + 0, acc.x);
  atomicAdd(c + 1, acc.y);
  atomicAdd(c + 2, acc.z);
  atomicAdd(c + 3, acc.w);
}

// ---------------------------------------------------------------------------
extern "C" void kernel_launch(void* const* d_in, const int* in_sizes, int n_in,
                              void* d_out, int out_size, void* d_ws,
                              size_t ws_size, hipStream_t stream) {
  const float* enc = (const float*)d_in[0];        // [B,T,E]
  const int* src_lens = (const int*)d_in[1];       // [B]
  const float* ds = (const float*)d_in[2];         // [B,D]
  // d_in[3] = mask (bool) -- recomputed from src_lens instead
  const float* We = (const float*)d_in[4];         // [E,H]
  const float* be = (const float*)d_in[5];         // [H]
  const float* Wd = (const float*)d_in[6];         // [D,H]
  const float* ww = (const float*)d_in[7];         // [H,1]
  const float* wb = (const float*)d_in[8];         // [1]

  float* ctx_out = (float*)d_out;                  // [B,E] at offset 0
  float* w_out = (float*)d_out + B * E;            // [B,T] after context

  float* ws = (float*)d_ws;
  float* dec_ws = ws;                              // B*H = 4096 floats
  float* erg_ws = ws + B * H;                      // B*T = 65536 floats

  dec_kernel<<<B, 512, 0, stream>>>(ds, Wd, be, dec_ws, ctx_out);
  erg_kernel<<<dim3(T / TB, B), 128, 0, stream>>>(enc, We, dec_ws, ww, wb, erg_ws);
  softmax_kernel<<<B, 256, 0, stream>>>(erg_ws, src_lens, w_out);
  ctx_kernel<<<dim3(T / 64, B), 128, 0, stream>>>(enc, w_out, ctx_out);
}

// Round 2
// 254.347 us; speedup vs baseline: 3.8885x; 3.8885x over previous
//
#include <hip/hip_runtime.h>
#include <hip/hip_bf16.h>

// Problem constants
#define B 32
#define T 2048
#define E 512
#define D 1024
#define H 128

typedef __attribute__((ext_vector_type(8))) short bf16x8;  // MFMA A/B frag (4 VGPRs)
typedef __attribute__((ext_vector_type(4))) float f32x4;   // MFMA C/D frag

static __device__ __forceinline__ short f2b(float f) {
  __hip_bfloat16 h = __float2bfloat16(f);  // HW RNE cvt
  return __builtin_bit_cast(short, h);
}

// ---------------------------------------------------------------------------
// Kernel 0: WeT[c][h][slot^(h&7)][j] = bf16(We[c*64 + slot*8 + j][h])
// Pre-swizzled transposed copy of W_enc so global_load_lds (linear LDS dest)
// lands a swizzled layout; ds_read_b128 B-frags then avoid 16-way conflicts.
// One 16B slot per thread. 8192 threads total.
// ---------------------------------------------------------------------------
__global__ __launch_bounds__(256) void wet_kernel(
    const float* __restrict__ We, char* __restrict__ WeT) {
  const int id = blockIdx.x * 256 + threadIdx.x;  // 0..8191
  const int c = id >> 10;                         // k-chunk 0..7
  const int rem = id & 1023;
  const int h = rem >> 3;                         // 0..127
  const int s = rem & 7;                          // slot 0..7
  const int k0 = c * 64 + s * 8;
  bf16x8 v;
#pragma unroll
  for (int j = 0; j < 8; ++j) v[j] = f2b(We[(k0 + j) * H + h]);
  *(bf16x8*)(WeT + c * 16384 + h * 128 + ((s ^ (h & 7)) * 16)) = v;
}

// ---------------------------------------------------------------------------
// Kernel 1: dec[b][h] = b_enc[h] + sum_k decoder_state[b][k] * W_dec[k][h]
// ---------------------------------------------------------------------------
__global__ __launch_bounds__(512) void dec_kernel(
    const float* __restrict__ ds, const float* __restrict__ Wd,
    const float* __restrict__ be, float* __restrict__ dec_ws) {
  const int b = blockIdx.x;
  const int tid = threadIdx.x;
  const int h = tid & 127;
  const int kg = tid >> 7;  // 0..3, each covers 256 k
  __shared__ float sds[D];
  __shared__ float sred[4][H];
  for (int i = tid; i < D; i += 512) sds[i] = ds[b * D + i];
  __syncthreads();
  float acc = 0.0f;
  const int k0 = kg * 256;
#pragma unroll 8
  for (int k = k0; k < k0 + 256; ++k) acc = fmaf(sds[k], Wd[k * H + h], acc);
  sred[kg][h] = acc;
  __syncthreads();
  if (kg == 0)
    dec_ws[b * H + h] = be[h] + sred[0][h] + sred[1][h] + sred[2][h] + sred[3][h];
}

// ---------------------------------------------------------------------------
// Kernel 2: erg via bf16 MFMA.
// Block = 256 thr = 4 waves; wave owns 16 rows (bt) x all 128 h; K=512 in
// 8 chunks of 64, double-buffered We-chunk in LDS via global_load_lds.
// A (enc) loaded fp32 direct from global per lane, HW-cvt to bf16.
// acc init = dec[b][h] (+b_enc already inside). Epilogue: tanh, dot w_w,
// 16-lane shuffle reduce -> erg_ws[bt].
// ---------------------------------------------------------------------------
__global__ __launch_bounds__(256, 3) void erg_mfma_kernel(
    const float* __restrict__ enc, const char* __restrict__ WeT,
    const float* __restrict__ dec_ws, const float* __restrict__ ww,
    const float* __restrict__ wb, float* __restrict__ erg_ws) {
  __shared__ __align__(16) char smem[2][16384];
  const int tid = threadIdx.x;
  const int w = tid >> 6;    // wave 0..3
  const int lane = tid & 63;
  const int m = lane & 15;   // A-row / D-col lane index
  const int g = lane >> 4;   // k-group 0..3
  const int row0 = blockIdx.x * 64 + w * 16;  // wave's 16 rows in [0, B*T)
  const int b = row0 >> 11;                   // T = 2048

  // acc init with dec (includes b_enc): D col = n*16 + m, all 4 row-regs same
  f32x4 acc[8];
#pragma unroll
  for (int n = 0; n < 8; ++n) {
    const float d = dec_ws[b * H + n * 16 + m];
    acc[n] = (f32x4){d, d, d, d};
  }

  const float* arow = enc + (size_t)(row0 + m) * E;  // A-frag row = lane&15

  // stage chunk 0
  {
    const char* gsrc = WeT + w * 4096 + lane * 16;
    char* ldst = (char*)&smem[0][w * 4096];
#pragma unroll
    for (int i = 0; i < 4; ++i)
      __builtin_amdgcn_global_load_lds(
          (const __attribute__((address_space(1))) void*)(gsrc + i * 1024),
          (__attribute__((address_space(3))) void*)(ldst + i * 1024), 16, 0, 0);
  }
  asm volatile("s_waitcnt vmcnt(0)" ::: "memory");
  __syncthreads();

  for (int c = 0; c < 8; ++c) {
    const int cur = c & 1;
    if (c < 7) {  // prefetch next chunk into other buffer
      const char* gsrc = WeT + (c + 1) * 16384 + w * 4096 + lane * 16;
      char* ldst = (char*)&smem[cur ^ 1][w * 4096];
#pragma unroll
      for (int i = 0; i < 4; ++i)
        __builtin_amdgcn_global_load_lds(
            (const __attribute__((address_space(1))) void*)(gsrc + i * 1024),
            (__attribute__((address_space(3))) void*)(ldst + i * 1024), 16, 0, 0);
    }
    // A loads: lane's 8 consecutive fp32 per k-step (2 k-steps/chunk)
    const float* ak = arow + c * 64 + g * 8;
    const float4 a0 = *(const float4*)(ak);
    const float4 a1 = *(const float4*)(ak + 4);
    const float4 a2 = *(const float4*)(ak + 32);
    const float4 a3 = *(const float4*)(ak + 36);
    bf16x8 af0, af1;
    af0[0] = f2b(a0.x); af0[1] = f2b(a0.y); af0[2] = f2b(a0.z); af0[3] = f2b(a0.w);
    af0[4] = f2b(a1.x); af0[5] = f2b(a1.y); af0[6] = f2b(a1.z); af0[7] = f2b(a1.w);
    af1[0] = f2b(a2.x); af1[1] = f2b(a2.y); af1[2] = f2b(a2.z); af1[3] = f2b(a2.w);
    af1[4] = f2b(a3.x); af1[5] = f2b(a3.y); af1[6] = f2b(a3.z); af1[7] = f2b(a3.w);

#pragma unroll
    for (int kk = 0; kk < 2; ++kk) {
      const int slot = (((kk * 4) + g) ^ (lane & 7)) * 16;
      const bf16x8 af = kk ? af1 : af0;
#pragma unroll
      for (int n = 0; n < 8; ++n) {
        const bf16x8 bf =
            *(const bf16x8*)(&smem[cur][(n * 16 + m) * 128 + slot]);
        acc[n] = __builtin_amdgcn_mfma_f32_16x16x32_bf16(af, bf, acc[n], 0, 0, 0);
      }
    }
    asm volatile("s_waitcnt vmcnt(0)" ::: "memory");
    __syncthreads();
  }

  // Epilogue: erg[row] = wb + sum_h ww[h] * tanh(acc). D: row=g*4+j, col=n*16+m.
  const float wbv = wb[0];
  float wwreg[8];
#pragma unroll
  for (int n = 0; n < 8; ++n) wwreg[n] = ww[n * 16 + m];
#pragma unroll
  for (int j = 0; j < 4; ++j) {
    float gsum = 0.0f;
#pragma unroll
    for (int n = 0; n < 8; ++n) {
      const float x = acc[n][j];
      const float th = 1.0f - 2.0f / (__expf(2.0f * x) + 1.0f);
      gsum = fmaf(wwreg[n], th, gsum);
    }
#pragma unroll
    for (int off = 1; off < 16; off <<= 1) gsum += __shfl_xor(gsum, off, 64);
    if (m == 0) erg_ws[row0 + g * 4 + j] = gsum + wbv;
  }
}

// ---------------------------------------------------------------------------
// Kernel 3: masked softmax over t (mask recomputed from src_lens)
// ---------------------------------------------------------------------------
__global__ __launch_bounds__(256) void softmax_kernel(
    const float* __restrict__ erg_ws, const int* __restrict__ src_lens,
    float* __restrict__ wout) {
  const int b = blockIdx.x;
  const int n = src_lens[b];
  const int tid = threadIdx.x;
  const int lane = tid & 63, wid = tid >> 6;
  __shared__ float sm[4];

  float v[T / 256];
  float mx = -1e30f;
#pragma unroll
  for (int r = 0; r < T / 256; ++r) {
    const int t = tid + r * 256;
    const float x = erg_ws[b * T + t];
    v[r] = (t < n) ? x : -1e30f;
    mx = fmaxf(mx, v[r]);
  }
#pragma unroll
  for (int off = 32; off > 0; off >>= 1) mx = fmaxf(mx, __shfl_xor(mx, off, 64));
  if (lane == 0) sm[wid] = mx;
  __syncthreads();
  mx = fmaxf(fmaxf(sm[0], sm[1]), fmaxf(sm[2], sm[3]));
  __syncthreads();

  float s = 0.0f;
#pragma unroll
  for (int r = 0; r < T / 256; ++r) {
    const float e = (v[r] > -1e29f) ? __expf(v[r] - mx) : 0.0f;
    v[r] = e;
    s += e;
  }
#pragma unroll
  for (int off = 32; off > 0; off >>= 1) s += __shfl_xor(s, off, 64);
  if (lane == 0) sm[wid] = s;
  __syncthreads();
  s = sm[0] + sm[1] + sm[2] + sm[3];
  const float inv = 1.0f / s;
#pragma unroll
  for (int r = 0; r < T / 256; ++r) wout[b * T + tid + r * 256] = v[r] * inv;
}

// ---------------------------------------------------------------------------
// Kernel 4: ctx partials (no atomics). Block = (chunk of 128 t) x b.
// 256 thr: e4 = tid&127 (float4 over E), tp = tid>>7 strides t by 2.
// part[(b*32 + chunk*2 + tp)*512 + e]
// ---------------------------------------------------------------------------
__global__ __launch_bounds__(256) void ctxp_kernel(
    const float* __restrict__ enc, const float* __restrict__ w,
    float* __restrict__ part) {
  const int b = blockIdx.y;
  const int ch = blockIdx.x;  // 0..15
  const int e4 = threadIdx.x & 127;
  const int tp = threadIdx.x >> 7;
  __shared__ float sw[128];
  if (threadIdx.x < 128) sw[threadIdx.x] = w[b * T + ch * 128 + threadIdx.x];
  __syncthreads();
  const float4* ep = (const float4*)(enc + ((size_t)b * T + ch * 128) * E) + e4;
  float4 acc = {0.0f, 0.0f, 0.0f, 0.0f};
#pragma unroll 8
  for (int t = tp; t < 128; t += 2) {
    const float4 e = ep[(size_t)t * (E / 4)];
    const float wv = sw[t];
    acc.x = fmaf(e.x, wv, acc.x);
    acc.y = fmaf(e.y, wv, acc.y);
    acc.z = fmaf(e.z, wv, acc.z);
    acc.w = fmaf(e.w, wv, acc.w);
  }
  *(float4*)(part + ((size_t)(b * 32 + ch * 2 + tp)) * E + e4 * 4) = acc;
}

// Kernel 5: reduce 32 partials -> ctx[b][e]
__global__ __launch_bounds__(128) void ctxr_kernel(
    const float* __restrict__ part, float* __restrict__ ctx) {
  const int b = blockIdx.x;
  const int e4 = threadIdx.x;  // 0..127
  float4 acc = {0.0f, 0.0f, 0.0f, 0.0f};
#pragma unroll
  for (int p = 0; p < 32; ++p) {
    const float4 v = *(const float4*)(part + ((size_t)(b * 32 + p)) * E + e4 * 4);
    acc.x += v.x; acc.y += v.y; acc.z += v.z; acc.w += v.w;
  }
  *(float4*)(ctx + b * E + e4 * 4) = acc;
}

// ---------------------------------------------------------------------------
extern "C" void kernel_launch(void* const* d_in, const int* in_sizes, int n_in,
                              void* d_out, int out_size, void* d_ws,
                              size_t ws_size, hipStream_t stream) {
  const float* enc = (const float*)d_in[0];   // [B,T,E]
  const int* src_lens = (const int*)d_in[1];  // [B]
  const float* ds = (const float*)d_in[2];    // [B,D]
  // d_in[3] = mask (bool) -- recomputed from src_lens
  const float* We = (const float*)d_in[4];    // [E,H]
  const float* be = (const float*)d_in[5];    // [H]
  const float* Wd = (const float*)d_in[6];    // [D,H]
  const float* ww = (const float*)d_in[7];    // [H,1]
  const float* wb = (const float*)d_in[8];    // [1]

  float* ctx_out = (float*)d_out;             // [B,E]
  float* w_out = (float*)d_out + B * E;       // [B,T]

  float* ws = (float*)d_ws;
  float* dec_ws = ws;                          // 4096 f
  float* erg_ws = ws + B * H;                  // 65536 f
  char* WeT = (char*)(ws + B * H + B * T);     // 128 KiB (bf16, swizzled)
  float* part = ws + B * H + B * T + 32768;    // 32*32*512 f = 2 MiB... (B*32*E = 524288 f)

  wet_kernel<<<32, 256, 0, stream>>>(We, WeT);
  dec_kernel<<<B, 512, 0, stream>>>(ds, Wd, be, dec_ws);
  erg_mfma_kernel<<<(B * T) / 64, 256, 0, stream>>>(enc, WeT, dec_ws, ww, wb, erg_ws);
  softmax_kernel<<<B, 256, 0, stream>>>(erg_ws, src_lens, w_out);
  ctxp_kernel<<<dim3(16, B), 256, 0, stream>>>(enc, w_out, part);
  ctxr_kernel<<<B, 128, 0, stream>>>(part, ctx_out);
}